// Round 7
// baseline (237.771 us; speedup 1.0000x reference)
//
#include <hip/hip_runtime.h>
#include <math.h>

#define B 8
#define S 2048
#define D 1024

// ---------------- reduction helpers (256-thread blocks) ----------------
__device__ __forceinline__ float waveReduceSum(float v) {
#pragma unroll
    for (int k = 32; k >= 1; k >>= 1) v += __shfl_xor(v, k, 64);
    return v;
}
__device__ __forceinline__ float waveReduceMax(float v) {
#pragma unroll
    for (int k = 32; k >= 1; k >>= 1) v = fmaxf(v, __shfl_xor(v, k, 64));
    return v;
}
__device__ float blockReduceSum(float v) {
    __shared__ float sm[4];
    int lane = threadIdx.x & 63, wid = threadIdx.x >> 6;
    v = waveReduceSum(v);
    __syncthreads();
    if (lane == 0) sm[wid] = v;
    __syncthreads();
    return sm[0] + sm[1] + sm[2] + sm[3];
}

// ---- init-free grid barrier for 128-block grids (one block/CU -> co-resident).
// ws is poisoned 0xAA each call, so flags start != magic; magics increase per barrier.
// Release-ordered flag store (after __threadfence) publishes prior writes;
// acquire-ordered spin load + __threadfence makes them visible.
__device__ __forceinline__ void gridBarrier128(unsigned* flags, unsigned magic) {
    __syncthreads();
    __threadfence();
    if (threadIdx.x == 0)
        __hip_atomic_store(&flags[blockIdx.x], magic, __ATOMIC_RELEASE, __HIP_MEMORY_SCOPE_AGENT);
    if (threadIdx.x < 128) {
        while (__hip_atomic_load(&flags[threadIdx.x], __ATOMIC_ACQUIRE,
                                 __HIP_MEMORY_SCOPE_AGENT) != magic)
            __builtin_amdgcn_s_sleep(1);
    }
    __syncthreads();
    __threadfence();
}

// ================= KA: q0 = x0@Wq+bq (+zero accs) | barrier | u = Wk@q0 ======
// grid 128, block 256.
__global__ void __launch_bounds__(256) kA(const float* __restrict__ x,
                                          const float* __restrict__ Wq,
                                          const float* __restrict__ bq,
                                          const float* __restrict__ Wk,
                                          float* __restrict__ q0,
                                          float* __restrict__ u,
                                          float* __restrict__ zero_region,
                                          unsigned* __restrict__ flagsA) {
    const int tid = threadIdx.x;
    const int bid = blockIdx.x;
    // zero wacc+hacc: 128 blocks x 128 floats = 16384
    if (tid < 128) zero_region[bid * 128 + tid] = 0.f;

    __shared__ float xs[8][1024];       // 32 KB
    __shared__ float red[16 * 16 * 9];  // 9 KB

    // ---- phase A (blocks 0..63): q0 = x0 @ Wq + bq, full-K per block ----
    if (bid < 64) {
        const int dp0 = bid * 16;
        const int dpl = tid & 15, kg = tid >> 4;
        for (int j = tid; j < 2048; j += 256) {  // 8 rows x 256 float4
            int b = j >> 8, off = j & 255;
            ((float4*)xs[b])[off] = ((const float4*)(x + (size_t)b * S * D))[off];
        }
        __syncthreads();
        float acc[8] = {0.f, 0.f, 0.f, 0.f, 0.f, 0.f, 0.f, 0.f};
        const int k0 = kg * 64;
        for (int i = 0; i < 64; ++i) {
            int k = k0 + i;
            float wv = Wq[(size_t)k * D + dp0 + dpl];
#pragma unroll
            for (int b = 0; b < 8; ++b) acc[b] += xs[b][k] * wv;
        }
#pragma unroll
        for (int b = 0; b < 8; ++b) red[(kg * 16 + dpl) * 9 + b] = acc[b];
        __syncthreads();
        if (tid < 128) {
            int dpl2 = tid >> 3, b = tid & 7;
            float s = 0.f;
#pragma unroll
            for (int g = 0; g < 16; ++g) s += red[(g * 16 + dpl2) * 9 + b];
            q0[b * D + dp0 + dpl2] = s + bq[dp0 + dpl2];
        }
    }

    gridBarrier128(flagsA, 1u);

    // ---- phase B: u rows bid*8 + wave*2 + {0,1} ----
    {
        const int wave = tid >> 6, lane = tid & 63;
        const int r0 = bid * 8 + wave * 2;
        const float4* W0 = (const float4*)(Wk + (size_t)r0 * D);
        const float4* W1 = (const float4*)(Wk + (size_t)(r0 + 1) * D);
        const float4* q04 = (const float4*)q0;
        float a0[8] = {0.f, 0.f, 0.f, 0.f, 0.f, 0.f, 0.f, 0.f};
        float a1[8] = {0.f, 0.f, 0.f, 0.f, 0.f, 0.f, 0.f, 0.f};
#pragma unroll
        for (int i = 0; i < 4; ++i) {
            float4 w0 = W0[lane + 64 * i];
            float4 w1 = W1[lane + 64 * i];
#pragma unroll
            for (int b = 0; b < 8; ++b) {
                float4 qv = q04[b * 256 + lane + 64 * i];
                a0[b] += w0.x * qv.x + w0.y * qv.y + w0.z * qv.z + w0.w * qv.w;
                a1[b] += w1.x * qv.x + w1.y * qv.y + w1.z * qv.z + w1.w * qv.w;
            }
        }
#pragma unroll
        for (int b = 0; b < 8; ++b) {
            float v0 = waveReduceSum(a0[b]);
            float v1 = waveReduceSum(a1[b]);
            if (lane == 0) {
                u[b * D + r0] = v0;
                u[b * D + r0 + 1] = v1;
            }
        }
    }
}

// ================= KB: fused scores + online-softmax partials (x once) =======
// grid (128, 8), block 256. Block: 16 t's of batch b.
__global__ void __launch_bounds__(256) k3_attn(const float* __restrict__ x,
                                               const float* __restrict__ u,
                                               float* __restrict__ pml,
                                               float* __restrict__ pw) {
    const int b = blockIdx.y;
    const int t0 = blockIdx.x * 16;
    const int tid = threadIdx.x;
    const int wave = tid >> 6, lane = tid & 63;
    const float4* xb4 = (const float4*)(x + (size_t)b * S * D);
    float4 xr[16];
#pragma unroll
    for (int t = 0; t < 16; ++t) xr[t] = xb4[(size_t)(t0 + t) * 256 + tid];
    float4 uv = ((const float4*)(u + b * D))[tid];
    __shared__ float part[16][256];
#pragma unroll
    for (int t = 0; t < 16; ++t)
        part[t][tid] = xr[t].x * uv.x + xr[t].y * uv.y + xr[t].z * uv.z + xr[t].w * uv.w;
    __syncthreads();
    __shared__ float s_sc[16];
#pragma unroll
    for (int r = 0; r < 4; ++r) {
        int t = wave * 4 + r;
        float v = part[t][lane] + part[t][lane + 64] + part[t][lane + 128] + part[t][lane + 192];
        v = waveReduceSum(v);
        if (lane == 0) s_sc[t] = v * 0.03125f;  // 1/sqrt(1024)
    }
    __syncthreads();
    float m = -INFINITY;
#pragma unroll
    for (int t = 0; t < 16; ++t) m = fmaxf(m, s_sc[t]);
    float p[16], l = 0.f;
#pragma unroll
    for (int t = 0; t < 16; ++t) {
        p[t] = __expf(s_sc[t] - m);
        l += p[t];
    }
    float4 wl = {0.f, 0.f, 0.f, 0.f};
#pragma unroll
    for (int t = 0; t < 16; ++t) {
        wl.x += p[t] * xr[t].x;
        wl.y += p[t] * xr[t].y;
        wl.z += p[t] * xr[t].z;
        wl.w += p[t] * xr[t].w;
    }
    const int pidx = b * 128 + blockIdx.x;
    ((float4*)(pw + (size_t)pidx * 1024))[tid] = wl;
    if (tid == 0) {
        pml[pidx * 2 + 0] = m;
        pml[pidx * 2 + 1] = l;
    }
}

// ================= KC: comb+@Wv | barrier | LN1+@Wd | barrier | final ========
// grid 128, block 256.
__global__ void __launch_bounds__(256) kC(const float* __restrict__ pml,
                                          const float* __restrict__ pw,
                                          const float* __restrict__ Wv,
                                          const float* __restrict__ bv,
                                          const float* __restrict__ x,
                                          const float* __restrict__ g1,
                                          const float* __restrict__ b1,
                                          const float* __restrict__ Wd,
                                          const float* __restrict__ bd,
                                          const float* __restrict__ g2,
                                          const float* __restrict__ b2,
                                          const float* __restrict__ Wc,
                                          const float* __restrict__ bc,
                                          float* __restrict__ wacc,
                                          float* __restrict__ hacc,
                                          unsigned* __restrict__ flagsC,
                                          float* __restrict__ out) {
    const int tid = threadIdx.x;
    const int bid = blockIdx.x;
    const int d0 = (bid >> 2) * 32;
    const int dp = (bid & 3) * 256 + tid;
    const int wave = tid >> 6, lane = tid & 63;
    __shared__ float pm[8][128], pl[8][128], sc[8][128];  // 12 KB
    __shared__ float sM[8], sL[8];
    __shared__ float vs[8][32];
    __shared__ float sMu[8], sInv[8];

    // ---- phase 1: combine partials (local 8x32 w slice) + @Wv -> wacc ----
    for (int j = tid; j < 1024; j += 256) {
        int b = j >> 7, blk = j & 127;
        pm[b][blk] = pml[(b * 128 + blk) * 2 + 0];
        pl[b][blk] = pml[(b * 128 + blk) * 2 + 1];
    }
    __syncthreads();
#pragma unroll
    for (int h = 0; h < 2; ++h) {
        int b = wave + h * 4;
        float mv = fmaxf(pm[b][lane], pm[b][lane + 64]);
        float M = waveReduceMax(mv);
        float lp = __expf(pm[b][lane] - M) * pl[b][lane] +
                   __expf(pm[b][lane + 64] - M) * pl[b][lane + 64];
        float L = waveReduceSum(lp);
        if (lane == 0) {
            sM[b] = M;
            sL[b] = L;
        }
    }
    __syncthreads();
    for (int j = tid; j < 1024; j += 256) {
        int b = j >> 7, blk = j & 127;
        sc[b][blk] = __expf(pm[b][blk] - sM[b]);
    }
    __syncthreads();
    {
        int b = tid >> 5, dd = tid & 31, d = d0 + dd;
        float acc = 0.f;
#pragma unroll 4
        for (int blk = 0; blk < 128; ++blk)
            acc += sc[b][blk] * pw[(size_t)(b * 128 + blk) * 1024 + d];
        vs[b][dd] = acc / sL[b];
    }
    __syncthreads();
    {
        float acc[8] = {0.f, 0.f, 0.f, 0.f, 0.f, 0.f, 0.f, 0.f};
#pragma unroll 4
        for (int dd = 0; dd < 32; ++dd) {
            float wv = Wv[(size_t)(d0 + dd) * D + dp];
#pragma unroll
            for (int b = 0; b < 8; ++b) acc[b] += vs[b][dd] * wv;
        }
#pragma unroll
        for (int b = 0; b < 8; ++b) atomicAdd(&wacc[b * D + dp], acc[b]);
    }

    gridBarrier128(flagsC, 1u);

    // ---- phase 2: LN1 stats (redundant per block) + local ln1 slice + @Wd ----
    for (int b = 0; b < 8; ++b) {
        float s = 0.f, ss = 0.f;
#pragma unroll
        for (int i = 0; i < 4; ++i) {
            int e = tid * 4 + i;
            float v = wacc[b * D + e] + bv[e] + x[(size_t)b * S * D + e];
            s += v;
            ss += v * v;
        }
        s = blockReduceSum(s);
        ss = blockReduceSum(ss);
        if (tid == 0) {
            float mu = s * (1.0f / D);
            sMu[b] = mu;
            sInv[b] = rsqrtf(ss * (1.0f / D) - mu * mu + 1e-5f);
        }
    }
    __syncthreads();
    {
        int b = tid >> 5, dd = tid & 31, d = d0 + dd;
        float v = wacc[b * D + d] + bv[d] + x[(size_t)b * S * D + d];
        vs[b][dd] = (v - sMu[b]) * sInv[b] * g1[d] + b1[d];
    }
    __syncthreads();
    {
        float acc[8] = {0.f, 0.f, 0.f, 0.f, 0.f, 0.f, 0.f, 0.f};
#pragma unroll 4
        for (int dd = 0; dd < 32; ++dd) {
            float wv = Wd[(size_t)(d0 + dd) * D + dp];
#pragma unroll
            for (int b = 0; b < 8; ++b) acc[b] += vs[b][dd] * wv;
        }
#pragma unroll
        for (int b = 0; b < 8; ++b) atomicAdd(&hacc[b * D + dp], acc[b]);
    }

    gridBarrier128(flagsC, 2u);

    // ---- phase 3 (blocks 0..7): ln1 recompute + ReLU + LN2 + classifier ----
    if (bid < 8) {
        const int b = bid;
        float r[4];
        float s = 0.f, ss = 0.f;
#pragma unroll
        for (int i = 0; i < 4; ++i) {
            int e = tid * 4 + i;
            float v = wacc[b * D + e] + bv[e] + x[(size_t)b * S * D + e];
            r[i] = v;
            s += v;
            ss += v * v;
        }
        s = blockReduceSum(s);
        ss = blockReduceSum(ss);
        float mu1 = s * (1.0f / D);
        float inv1 = rsqrtf(ss * (1.0f / D) - mu1 * mu1 + 1e-5f);
        float t[4];
        float s2 = 0.f, ss2 = 0.f;
#pragma unroll
        for (int i = 0; i < 4; ++i) {
            int e = tid * 4 + i;
            float ln1v = (r[i] - mu1) * inv1 * g1[e] + b1[e];
            float h = fmaxf(hacc[b * D + e] + bd[e], 0.f) + ln1v;
            t[i] = h;
            s2 += h;
            ss2 += h * h;
        }
        s2 = blockReduceSum(s2);
        ss2 = blockReduceSum(ss2);
        float mu2 = s2 * (1.0f / D);
        float inv2 = rsqrtf(ss2 * (1.0f / D) - mu2 * mu2 + 1e-5f);
        float p0 = 0.f, p1 = 0.f;
#pragma unroll
        for (int i = 0; i < 4; ++i) {
            int e = tid * 4 + i;
            float l2 = (t[i] - mu2) * inv2 * g2[e] + b2[e];
            p0 += l2 * Wc[e * 2 + 0];
            p1 += l2 * Wc[e * 2 + 1];
        }
        p0 = blockReduceSum(p0);
        p1 = blockReduceSum(p1);
        if (tid == 0) {
            out[b * 2 + 0] = p0 + bc[0];
            out[b * 2 + 1] = p1 + bc[1];
        }
    }
}

extern "C" void kernel_launch(void* const* d_in, const int* in_sizes, int n_in,
                              void* d_out, int out_size, void* d_ws, size_t ws_size,
                              hipStream_t stream) {
    const float* x  = (const float*)d_in[0];
    const float* Wq = (const float*)d_in[1];
    const float* bq = (const float*)d_in[2];
    const float* Wk = (const float*)d_in[3];
    // bk (d_in[4]): constant over t -> cancels in softmax
    const float* Wv = (const float*)d_in[5];
    const float* bv = (const float*)d_in[6];
    const float* Wd = (const float*)d_in[7];
    const float* bd = (const float*)d_in[8];
    const float* g1 = (const float*)d_in[9];
    const float* b1 = (const float*)d_in[10];
    const float* g2 = (const float*)d_in[11];
    const float* b2 = (const float*)d_in[12];
    const float* Wc = (const float*)d_in[13];
    const float* bc = (const float*)d_in[14];
    float* out = (float*)d_out;

    float* ws   = (float*)d_ws;
    float* q0   = ws;            // [8,1024]
    float* u    = ws + 8192;     // [8,1024]
    float* wacc = ws + 16384;    // [8,1024] zeroed by kA, atomics in kC p1
    float* hacc = ws + 24576;    // [8,1024] zeroed by kA, atomics in kC p2
    float* pml  = ws + 32768;    // [8,128,2]
    float* pw   = ws + 34816;    // [8,128,1024] (byte off 139264, 16B-aligned)
    unsigned* flagsA = (unsigned*)(ws + 34816 + 1048576);  // 128 u32 (poison-init barrier)
    unsigned* flagsC = flagsA + 128;                       // 128 u32

    // KA: q0 = x0@Wq+bq, zero wacc/hacc | barrier | u = Wk@q0
    kA<<<128, 256, 0, stream>>>(x, Wq, bq, Wk, q0, u, wacc, flagsA);
    // KB: attention partials (single x pass)
    k3_attn<<<dim3(128, 8), 256, 0, stream>>>(x, u, pml, pw);
    // KC: combine+@Wv | barrier | LN1+@Wd | barrier | final
    kC<<<128, 256, 0, stream>>>(pml, pw, Wv, bv, x, g1, b1, Wd, bd, g2, b2, Wc, bc,
                                wacc, hacc, flagsC, out);
}

// Round 8
// 225.726 us; speedup vs baseline: 1.0534x; 1.0534x over previous
//
#include <hip/hip_runtime.h>
#include <math.h>

#define B 8
#define S 2048
#define D 1024

// ---------------- reduction helpers (256-thread blocks) ----------------
__device__ __forceinline__ float waveReduceSum(float v) {
#pragma unroll
    for (int k = 32; k >= 1; k >>= 1) v += __shfl_xor(v, k, 64);
    return v;
}
__device__ __forceinline__ float waveReduceMax(float v) {
#pragma unroll
    for (int k = 32; k >= 1; k >>= 1) v = fmaxf(v, __shfl_xor(v, k, 64));
    return v;
}
__device__ float blockReduceSum(float v) {
    __shared__ float sm[4];
    int lane = threadIdx.x & 63, wid = threadIdx.x >> 6;
    v = waveReduceSum(v);
    __syncthreads();
    if (lane == 0) sm[wid] = v;
    __syncthreads();
    return sm[0] + sm[1] + sm[2] + sm[3];
}

// ---- barrier A: poison-init per-block flags (no prior zeroing available).
// Low contention: only wave 0 polls (64 lanes x 2 flags + __all), ~0.85us period.
__device__ __forceinline__ void barrierScan128(unsigned* flags, unsigned magic) {
    __syncthreads();
    __threadfence();
    if (threadIdx.x == 0)
        __hip_atomic_store(&flags[blockIdx.x], magic, __ATOMIC_RELEASE, __HIP_MEMORY_SCOPE_AGENT);
    if (threadIdx.x < 64) {
        const int lane = threadIdx.x;
        for (;;) {
            bool ok = (__hip_atomic_load(&flags[lane], __ATOMIC_RELAXED,
                                         __HIP_MEMORY_SCOPE_AGENT) == magic) &&
                      (__hip_atomic_load(&flags[lane + 64], __ATOMIC_RELAXED,
                                         __HIP_MEMORY_SCOPE_AGENT) == magic);
            if (__all(ok)) break;
            __builtin_amdgcn_s_sleep(32);  // ~2048 cyc ~0.85us
        }
    }
    __syncthreads();
    __threadfence();
}

// ---- barrier C: counter + single release flag (cnt/rel pre-zeroed by kA).
// 128 arrivals via atomicAdd; 128 pollers (thread 0/block) on ONE address.
__device__ __forceinline__ void barrierCnt128(unsigned* cnt, unsigned* rel, unsigned magic) {
    __syncthreads();
    __threadfence();
    if (threadIdx.x == 0) {
        if (atomicAdd(cnt, 1u) == 127u)
            __hip_atomic_store(rel, magic, __ATOMIC_RELEASE, __HIP_MEMORY_SCOPE_AGENT);
        while (__hip_atomic_load(rel, __ATOMIC_ACQUIRE, __HIP_MEMORY_SCOPE_AGENT) != magic)
            __builtin_amdgcn_s_sleep(32);
    }
    __syncthreads();
    __threadfence();
}

// ================= KA: q0 = x0@Wq+bq (+zero accs & barC) | barrier | u = Wk@q0
// grid 128, block 256.
__global__ void __launch_bounds__(256) kA(const float* __restrict__ x,
                                          const float* __restrict__ Wq,
                                          const float* __restrict__ bq,
                                          const float* __restrict__ Wk,
                                          float* __restrict__ q0,
                                          float* __restrict__ u,
                                          float* __restrict__ zero_region,
                                          unsigned* __restrict__ flagsA,
                                          unsigned* __restrict__ barC) {
    const int tid = threadIdx.x;
    const int bid = blockIdx.x;
    // zero wacc+hacc: 128 blocks x 128 floats = 16384; block 0 zeroes barC words
    if (tid < 128) zero_region[bid * 128 + tid] = 0.f;
    if (bid == 0 && tid >= 128 && tid < 132) barC[tid - 128] = 0u;

    __shared__ float xs[8][1024];       // 32 KB
    __shared__ float red[16 * 16 * 9];  // 9 KB

    // ---- phase A (blocks 0..63): q0 = x0 @ Wq + bq, full-K per block ----
    if (bid < 64) {
        const int dp0 = bid * 16;
        const int dpl = tid & 15, kg = tid >> 4;
        for (int j = tid; j < 2048; j += 256) {  // 8 rows x 256 float4
            int b = j >> 8, off = j & 255;
            ((float4*)xs[b])[off] = ((const float4*)(x + (size_t)b * S * D))[off];
        }
        __syncthreads();
        float acc[8] = {0.f, 0.f, 0.f, 0.f, 0.f, 0.f, 0.f, 0.f};
        const int k0 = kg * 64;
        for (int i = 0; i < 64; ++i) {
            int k = k0 + i;
            float wv = Wq[(size_t)k * D + dp0 + dpl];
#pragma unroll
            for (int b = 0; b < 8; ++b) acc[b] += xs[b][k] * wv;
        }
#pragma unroll
        for (int b = 0; b < 8; ++b) red[(kg * 16 + dpl) * 9 + b] = acc[b];
        __syncthreads();
        if (tid < 128) {
            int dpl2 = tid >> 3, b = tid & 7;
            float s = 0.f;
#pragma unroll
            for (int g = 0; g < 16; ++g) s += red[(g * 16 + dpl2) * 9 + b];
            q0[b * D + dp0 + dpl2] = s + bq[dp0 + dpl2];
        }
    }

    barrierScan128(flagsA, 1u);

    // ---- phase B: u rows bid*8 + wave*2 + {0,1} ----
    {
        const int wave = tid >> 6, lane = tid & 63;
        const int r0 = bid * 8 + wave * 2;
        const float4* W0 = (const float4*)(Wk + (size_t)r0 * D);
        const float4* W1 = (const float4*)(Wk + (size_t)(r0 + 1) * D);
        const float4* q04 = (const float4*)q0;
        float a0[8] = {0.f, 0.f, 0.f, 0.f, 0.f, 0.f, 0.f, 0.f};
        float a1[8] = {0.f, 0.f, 0.f, 0.f, 0.f, 0.f, 0.f, 0.f};
#pragma unroll
        for (int i = 0; i < 4; ++i) {
            float4 w0 = W0[lane + 64 * i];
            float4 w1 = W1[lane + 64 * i];
#pragma unroll
            for (int b = 0; b < 8; ++b) {
                float4 qv = q04[b * 256 + lane + 64 * i];
                a0[b] += w0.x * qv.x + w0.y * qv.y + w0.z * qv.z + w0.w * qv.w;
                a1[b] += w1.x * qv.x + w1.y * qv.y + w1.z * qv.z + w1.w * qv.w;
            }
        }
#pragma unroll
        for (int b = 0; b < 8; ++b) {
            float v0 = waveReduceSum(a0[b]);
            float v1 = waveReduceSum(a1[b]);
            if (lane == 0) {
                u[b * D + r0] = v0;
                u[b * D + r0 + 1] = v1;
            }
        }
    }
}

// ================= KB: fused scores + online-softmax partials (x once) =======
// grid (128, 8), block 256. Block: 16 t's of batch b.
__global__ void __launch_bounds__(256) k3_attn(const float* __restrict__ x,
                                               const float* __restrict__ u,
                                               float* __restrict__ pml,
                                               float* __restrict__ pw) {
    const int b = blockIdx.y;
    const int t0 = blockIdx.x * 16;
    const int tid = threadIdx.x;
    const int wave = tid >> 6, lane = tid & 63;
    const float4* xb4 = (const float4*)(x + (size_t)b * S * D);
    float4 xr[16];
#pragma unroll
    for (int t = 0; t < 16; ++t) xr[t] = xb4[(size_t)(t0 + t) * 256 + tid];
    float4 uv = ((const float4*)(u + b * D))[tid];
    __shared__ float part[16][256];
#pragma unroll
    for (int t = 0; t < 16; ++t)
        part[t][tid] = xr[t].x * uv.x + xr[t].y * uv.y + xr[t].z * uv.z + xr[t].w * uv.w;
    __syncthreads();
    __shared__ float s_sc[16];
#pragma unroll
    for (int r = 0; r < 4; ++r) {
        int t = wave * 4 + r;
        float v = part[t][lane] + part[t][lane + 64] + part[t][lane + 128] + part[t][lane + 192];
        v = waveReduceSum(v);
        if (lane == 0) s_sc[t] = v * 0.03125f;  // 1/sqrt(1024)
    }
    __syncthreads();
    float m = -INFINITY;
#pragma unroll
    for (int t = 0; t < 16; ++t) m = fmaxf(m, s_sc[t]);
    float p[16], l = 0.f;
#pragma unroll
    for (int t = 0; t < 16; ++t) {
        p[t] = __expf(s_sc[t] - m);
        l += p[t];
    }
    float4 wl = {0.f, 0.f, 0.f, 0.f};
#pragma unroll
    for (int t = 0; t < 16; ++t) {
        wl.x += p[t] * xr[t].x;
        wl.y += p[t] * xr[t].y;
        wl.z += p[t] * xr[t].z;
        wl.w += p[t] * xr[t].w;
    }
    const int pidx = b * 128 + blockIdx.x;
    ((float4*)(pw + (size_t)pidx * 1024))[tid] = wl;
    if (tid == 0) {
        pml[pidx * 2 + 0] = m;
        pml[pidx * 2 + 1] = l;
    }
}

// ================= KC: comb+@Wv | barrier | LN1+@Wd | barrier | final ========
// grid 128, block 256.
__global__ void __launch_bounds__(256) kC(const float* __restrict__ pml,
                                          const float* __restrict__ pw,
                                          const float* __restrict__ Wv,
                                          const float* __restrict__ bv,
                                          const float* __restrict__ x,
                                          const float* __restrict__ g1,
                                          const float* __restrict__ b1,
                                          const float* __restrict__ Wd,
                                          const float* __restrict__ bd,
                                          const float* __restrict__ g2,
                                          const float* __restrict__ b2,
                                          const float* __restrict__ Wc,
                                          const float* __restrict__ bc,
                                          float* __restrict__ wacc,
                                          float* __restrict__ hacc,
                                          unsigned* __restrict__ barC,
                                          float* __restrict__ out) {
    const int tid = threadIdx.x;
    const int bid = blockIdx.x;
    const int d0 = (bid >> 2) * 32;
    const int dp = (bid & 3) * 256 + tid;
    const int wave = tid >> 6, lane = tid & 63;
    __shared__ float pm[8][128], pl[8][128], sc[8][128];  // 12 KB
    __shared__ float sM[8], sL[8];
    __shared__ float vs[8][32];
    __shared__ float sMu[8], sInv[8];

    // ---- phase 1: combine partials (local 8x32 w slice) + @Wv -> wacc ----
    for (int j = tid; j < 1024; j += 256) {
        int b = j >> 7, blk = j & 127;
        pm[b][blk] = pml[(b * 128 + blk) * 2 + 0];
        pl[b][blk] = pml[(b * 128 + blk) * 2 + 1];
    }
    __syncthreads();
#pragma unroll
    for (int h = 0; h < 2; ++h) {
        int b = wave + h * 4;
        float mv = fmaxf(pm[b][lane], pm[b][lane + 64]);
        float M = waveReduceMax(mv);
        float lp = __expf(pm[b][lane] - M) * pl[b][lane] +
                   __expf(pm[b][lane + 64] - M) * pl[b][lane + 64];
        float L = waveReduceSum(lp);
        if (lane == 0) {
            sM[b] = M;
            sL[b] = L;
        }
    }
    __syncthreads();
    for (int j = tid; j < 1024; j += 256) {
        int b = j >> 7, blk = j & 127;
        sc[b][blk] = __expf(pm[b][blk] - sM[b]);
    }
    __syncthreads();
    {
        int b = tid >> 5, dd = tid & 31, d = d0 + dd;
        float acc = 0.f;
#pragma unroll 4
        for (int blk = 0; blk < 128; ++blk)
            acc += sc[b][blk] * pw[(size_t)(b * 128 + blk) * 1024 + d];
        vs[b][dd] = acc / sL[b];
    }
    __syncthreads();
    {
        float acc[8] = {0.f, 0.f, 0.f, 0.f, 0.f, 0.f, 0.f, 0.f};
#pragma unroll 4
        for (int dd = 0; dd < 32; ++dd) {
            float wv = Wv[(size_t)(d0 + dd) * D + dp];
#pragma unroll
            for (int b = 0; b < 8; ++b) acc[b] += vs[b][dd] * wv;
        }
#pragma unroll
        for (int b = 0; b < 8; ++b) atomicAdd(&wacc[b * D + dp], acc[b]);
    }

    barrierCnt128(&barC[0], &barC[1], 1u);

    // ---- phase 2: LN1 stats (per-wave rows) + local ln1 slice + @Wd ----
    {
        const float4* wacc4 = (const float4*)wacc;
        const float4* bv4 = (const float4*)bv;
#pragma unroll
        for (int h = 0; h < 2; ++h) {
            int b = wave + h * 4;
            const float4* xb4r = (const float4*)(x + (size_t)b * S * D);
            float s = 0.f, ss = 0.f;
#pragma unroll
            for (int i = 0; i < 4; ++i) {
                int idx = lane + 64 * i;
                float4 wv = wacc4[b * 256 + idx];
                float4 bb = bv4[idx];
                float4 xv = xb4r[idx];
                float v0 = wv.x + bb.x + xv.x;
                float v1 = wv.y + bb.y + xv.y;
                float v2 = wv.z + bb.z + xv.z;
                float v3 = wv.w + bb.w + xv.w;
                s += v0 + v1 + v2 + v3;
                ss += v0 * v0 + v1 * v1 + v2 * v2 + v3 * v3;
            }
            s = waveReduceSum(s);
            ss = waveReduceSum(ss);
            if (lane == 0) {
                float mu = s * (1.0f / D);
                sMu[b] = mu;
                sInv[b] = rsqrtf(ss * (1.0f / D) - mu * mu + 1e-5f);
            }
        }
    }
    __syncthreads();
    {
        int b = tid >> 5, dd = tid & 31, d = d0 + dd;
        float v = wacc[b * D + d] + bv[d] + x[(size_t)b * S * D + d];
        vs[b][dd] = (v - sMu[b]) * sInv[b] * g1[d] + b1[d];
    }
    __syncthreads();
    {
        float acc[8] = {0.f, 0.f, 0.f, 0.f, 0.f, 0.f, 0.f, 0.f};
#pragma unroll 4
        for (int dd = 0; dd < 32; ++dd) {
            float wv = Wd[(size_t)(d0 + dd) * D + dp];
#pragma unroll
            for (int b = 0; b < 8; ++b) acc[b] += vs[b][dd] * wv;
        }
#pragma unroll
        for (int b = 0; b < 8; ++b) atomicAdd(&hacc[b * D + dp], acc[b]);
    }

    barrierCnt128(&barC[2], &barC[3], 1u);

    // ---- phase 3 (blocks 0..7): ln1 recompute + ReLU + LN2 + classifier ----
    if (bid < 8) {
        const int b = bid;
        float r[4];
        float s = 0.f, ss = 0.f;
#pragma unroll
        for (int i = 0; i < 4; ++i) {
            int e = tid * 4 + i;
            float v = wacc[b * D + e] + bv[e] + x[(size_t)b * S * D + e];
            r[i] = v;
            s += v;
            ss += v * v;
        }
        s = blockReduceSum(s);
        ss = blockReduceSum(ss);
        float mu1 = s * (1.0f / D);
        float inv1 = rsqrtf(ss * (1.0f / D) - mu1 * mu1 + 1e-5f);
        float t[4];
        float s2 = 0.f, ss2 = 0.f;
#pragma unroll
        for (int i = 0; i < 4; ++i) {
            int e = tid * 4 + i;
            float ln1v = (r[i] - mu1) * inv1 * g1[e] + b1[e];
            float h = fmaxf(hacc[b * D + e] + bd[e], 0.f) + ln1v;
            t[i] = h;
            s2 += h;
            ss2 += h * h;
        }
        s2 = blockReduceSum(s2);
        ss2 = blockReduceSum(ss2);
        float mu2 = s2 * (1.0f / D);
        float inv2 = rsqrtf(ss2 * (1.0f / D) - mu2 * mu2 + 1e-5f);
        float p0 = 0.f, p1 = 0.f;
#pragma unroll
        for (int i = 0; i < 4; ++i) {
            int e = tid * 4 + i;
            float l2 = (t[i] - mu2) * inv2 * g2[e] + b2[e];
            p0 += l2 * Wc[e * 2 + 0];
            p1 += l2 * Wc[e * 2 + 1];
        }
        p0 = blockReduceSum(p0);
        p1 = blockReduceSum(p1);
        if (tid == 0) {
            out[b * 2 + 0] = p0 + bc[0];
            out[b * 2 + 1] = p1 + bc[1];
        }
    }
}

extern "C" void kernel_launch(void* const* d_in, const int* in_sizes, int n_in,
                              void* d_out, int out_size, void* d_ws, size_t ws_size,
                              hipStream_t stream) {
    const float* x  = (const float*)d_in[0];
    const float* Wq = (const float*)d_in[1];
    const float* bq = (const float*)d_in[2];
    const float* Wk = (const float*)d_in[3];
    // bk (d_in[4]): constant over t -> cancels in softmax
    const float* Wv = (const float*)d_in[5];
    const float* bv = (const float*)d_in[6];
    const float* Wd = (const float*)d_in[7];
    const float* bd = (const float*)d_in[8];
    const float* g1 = (const float*)d_in[9];
    const float* b1 = (const float*)d_in[10];
    const float* g2 = (const float*)d_in[11];
    const float* b2 = (const float*)d_in[12];
    const float* Wc = (const float*)d_in[13];
    const float* bc = (const float*)d_in[14];
    float* out = (float*)d_out;

    float* ws   = (float*)d_ws;
    float* q0   = ws;            // [8,1024]
    float* u    = ws + 8192;     // [8,1024]
    float* wacc = ws + 16384;    // [8,1024] zeroed by kA, atomics in kC p1
    float* hacc = ws + 24576;    // [8,1024] zeroed by kA, atomics in kC p2
    float* pml  = ws + 32768;    // [8,128,2]
    float* pw   = ws + 34816;    // [8,128,1024] (byte off 139264, 16B-aligned)
    unsigned* flagsA = (unsigned*)(ws + 34816 + 1048576);  // 128 u32, poison-init
    unsigned* barC   = flagsA + 128;                       // 4 u32 {cnt1,rel1,cnt2,rel2}, zeroed by kA

    // KA: q0 = x0@Wq+bq, zero wacc/hacc/barC | barrier | u = Wk@q0
    kA<<<128, 256, 0, stream>>>(x, Wq, bq, Wk, q0, u, wacc, flagsA, barC);
    // KB: attention partials (single x pass)
    k3_attn<<<dim3(128, 8), 256, 0, stream>>>(x, u, pml, pw);
    // KC: combine+@Wv | barrier | LN1+@Wd | barrier | final
    kC<<<128, 256, 0, stream>>>(pml, pw, Wv, bv, x, g1, b1, Wd, bd, g2, b2, Wc, bc,
                                wacc, hacc, barC, out);
}

// Round 9
// 183.693 us; speedup vs baseline: 1.2944x; 1.2288x over previous
//
#include <hip/hip_runtime.h>
#include <math.h>

#define B 8
#define S 2048
#define D 1024

// ---------------- reduction helpers (256-thread blocks) ----------------
__device__ __forceinline__ float waveReduceSum(float v) {
#pragma unroll
    for (int k = 32; k >= 1; k >>= 1) v += __shfl_xor(v, k, 64);
    return v;
}
__device__ float blockReduceSum(float v) {
    __shared__ float sm[4];
    int lane = threadIdx.x & 63, wid = threadIdx.x >> 6;
    v = waveReduceSum(v);
    __syncthreads();
    if (lane == 0) sm[wid] = v;
    __syncthreads();
    return sm[0] + sm[1] + sm[2] + sm[3];
}

// ---------------- K1: q0 = x0 @ Wq + bq (non-atomic, full-K per block) -------
// grid 64, block 256. Block owns a 16-wide dp chunk; 16 K-groups of 64.
// Also zeroes the atomic accumulators: wnum+wacc+hacc+wden = 24584 floats.
__global__ void __launch_bounds__(256) k1_q0(const float* __restrict__ x,
                                             const float* __restrict__ Wq,
                                             const float* __restrict__ bq,
                                             float* __restrict__ q0,
                                             float* __restrict__ zero_region) {
    const int tid = threadIdx.x;
    {
        int base = blockIdx.x * 384 + tid;  // 64 blocks x 384 >= 24584
#pragma unroll
        for (int r = 0; r < 2; ++r) {
            int idx = base + r * 256;
            if (idx < blockIdx.x * 384 + 384 && idx < 24584) zero_region[idx] = 0.f;
        }
    }

    const int dp0 = blockIdx.x * 16;
    const int dpl = tid & 15, kg = tid >> 4;
    __shared__ float xs[8][1024];
    for (int j = tid; j < 2048; j += 256) {  // 2048 float4 = 8 rows x 256
        int b = j >> 8, off = j & 255;
        ((float4*)xs[b])[off] = ((const float4*)(x + (size_t)b * S * D))[off];
    }
    __syncthreads();
    float acc[8] = {0.f, 0.f, 0.f, 0.f, 0.f, 0.f, 0.f, 0.f};
    const int k0 = kg * 64;
    for (int i = 0; i < 64; ++i) {
        int k = k0 + i;
        float wv = Wq[(size_t)k * D + dp0 + dpl];
#pragma unroll
        for (int b = 0; b < 8; ++b) acc[b] += xs[b][k] * wv;
    }
    __shared__ float red[16 * 16 * 9];  // (kg*16+dpl)*9 + b, pad stride 9
#pragma unroll
    for (int b = 0; b < 8; ++b) red[(kg * 16 + dpl) * 9 + b] = acc[b];
    __syncthreads();
    if (tid < 128) {
        int dpl2 = tid >> 3, b = tid & 7;
        float s = 0.f;
#pragma unroll
        for (int g = 0; g < 16; ++g) s += red[(g * 16 + dpl2) * 9 + b];
        q0[b * D + dp0 + dpl2] = s + bq[dp0 + dpl2];
    }
}

// ---------------- K2: u[b,row] = Wk[row,:] . q0[b,:] (one wave per row) ------
__global__ void __launch_bounds__(256) k2_u(const float* __restrict__ Wk,
                                            const float* __restrict__ q0,
                                            float* __restrict__ u) {
    int wid = (blockIdx.x * 256 + threadIdx.x) >> 6;  // row 0..1023
    int lane = threadIdx.x & 63;
    const float4* Wk4 = (const float4*)(Wk + (size_t)wid * D);
    const float4* q04 = (const float4*)q0;
    float acc[8] = {0.f, 0.f, 0.f, 0.f, 0.f, 0.f, 0.f, 0.f};
#pragma unroll
    for (int i = 0; i < 4; ++i) {
        float4 wv = Wk4[lane + 64 * i];
#pragma unroll
        for (int b = 0; b < 8; ++b) {
            float4 qv = q04[b * 256 + lane + 64 * i];
            acc[b] += wv.x * qv.x + wv.y * qv.y + wv.z * qv.z + wv.w * qv.w;
        }
    }
#pragma unroll
    for (int b = 0; b < 8; ++b) {
        float v = waveReduceSum(acc[b]);
        if (lane == 0) u[b * D + wid] = v;
    }
}

// ---------------- K3: fused scores + RAW-exp weighted sums (x once, in regs) -
// grid (128, 8), block 256. Block: 16 t's of batch b.
// Scores ~N(0,1) (x~N(0,1), 1/sqrt(D)-scaled weights) => exp without max-sub
// is safe in fp32. Accumulate wnum[b,d] += sum_t e^{s_t} x[t,d], wden[b] += sum e^{s_t}.
__global__ void __launch_bounds__(256) k3_attn(const float* __restrict__ x,
                                               const float* __restrict__ u,
                                               float* __restrict__ wnum,
                                               float* __restrict__ wden) {
    const int b = blockIdx.y;
    const int t0 = blockIdx.x * 16;
    const int tid = threadIdx.x;
    const int wave = tid >> 6, lane = tid & 63;
    const float4* xb4 = (const float4*)(x + (size_t)b * S * D);
    float4 xr[16];
#pragma unroll
    for (int t = 0; t < 16; ++t) xr[t] = xb4[(size_t)(t0 + t) * 256 + tid];
    float4 uv = ((const float4*)(u + b * D))[tid];
    __shared__ float part[16][256];
#pragma unroll
    for (int t = 0; t < 16; ++t)
        part[t][tid] = xr[t].x * uv.x + xr[t].y * uv.y + xr[t].z * uv.z + xr[t].w * uv.w;
    __syncthreads();
    __shared__ float s_sc[16];
#pragma unroll
    for (int r = 0; r < 4; ++r) {
        int t = wave * 4 + r;
        float v = part[t][lane] + part[t][lane + 64] + part[t][lane + 128] + part[t][lane + 192];
        v = waveReduceSum(v);
        if (lane == 0) s_sc[t] = v * 0.03125f;  // 1/sqrt(1024)
    }
    __syncthreads();
    float p[16], l = 0.f;
#pragma unroll
    for (int t = 0; t < 16; ++t) {
        p[t] = __expf(s_sc[t]);
        l += p[t];
    }
    float4 wl = {0.f, 0.f, 0.f, 0.f};
#pragma unroll
    for (int t = 0; t < 16; ++t) {
        wl.x += p[t] * xr[t].x;
        wl.y += p[t] * xr[t].y;
        wl.z += p[t] * xr[t].z;
        wl.w += p[t] * xr[t].w;
    }
    float* wd = wnum + b * D + tid * 4;
    atomicAdd(wd + 0, wl.x);
    atomicAdd(wd + 1, wl.y);
    atomicAdd(wd + 2, wl.z);
    atomicAdd(wd + 3, wl.w);
    if (tid == 0) atomicAdd(&wden[b], l);
}

// ---------------- K4: w = wnum/wden, wacc += w @ Wv (split-K) ----------------
// grid 128, block 256. K-chunk d0=(bid>>2)*32, dp-chunk (bid&3)*256.
__global__ void __launch_bounds__(256) k4_wv(const float* __restrict__ wnum,
                                             const float* __restrict__ wden,
                                             const float* __restrict__ Wv,
                                             float* __restrict__ wacc) {
    const int tid = threadIdx.x;
    const int bid = blockIdx.x;
    const int d0 = (bid >> 2) * 32;
    const int dp = (bid & 3) * 256 + tid;
    __shared__ float vs[8][32];
    __shared__ float sInv[8];
    if (tid < 8) sInv[tid] = 1.0f / wden[tid];
    __syncthreads();
    if (tid < 8 * 32) {
        int b = tid >> 5, dd = tid & 31;
        vs[b][dd] = wnum[b * D + d0 + dd] * sInv[b];
    }
    __syncthreads();
    float acc[8] = {0.f, 0.f, 0.f, 0.f, 0.f, 0.f, 0.f, 0.f};
#pragma unroll 4
    for (int dd = 0; dd < 32; ++dd) {
        float wv = Wv[(size_t)(d0 + dd) * D + dp];
#pragma unroll
        for (int b = 0; b < 8; ++b) acc[b] += vs[b][dd] * wv;
    }
#pragma unroll
    for (int b = 0; b < 8; ++b) atomicAdd(&wacc[b * D + dp], acc[b]);
}

// ---------------- K5: redundant LN1 slice + vecmat Wd -> hacc ----------------
// grid 128, block 256.
__global__ void __launch_bounds__(256) k5_ln1_wd(const float* __restrict__ wacc,
                                                 const float* __restrict__ bv,
                                                 const float* __restrict__ x,
                                                 const float* __restrict__ g1,
                                                 const float* __restrict__ b1,
                                                 const float* __restrict__ Wd,
                                                 float* __restrict__ hacc) {
    const int tid = threadIdx.x;
    const int bid = blockIdx.x;
    const int d0 = (bid >> 2) * 32;
    const int dp = (bid & 3) * 256 + tid;
    __shared__ float sMu[8], sInv[8], vs[8][32];
    for (int b = 0; b < 8; ++b) {
        float s = 0.f, ss = 0.f;
#pragma unroll
        for (int i = 0; i < 4; ++i) {
            int e = tid * 4 + i;
            float v = wacc[b * D + e] + bv[e] + x[(size_t)b * S * D + e];
            s += v;
            ss += v * v;
        }
        s = blockReduceSum(s);
        ss = blockReduceSum(ss);
        if (tid == 0) {
            float mu = s * (1.0f / D);
            sMu[b] = mu;
            sInv[b] = rsqrtf(ss * (1.0f / D) - mu * mu + 1e-5f);
        }
    }
    __syncthreads();
    {
        int b = tid >> 5, dd = tid & 31, d = d0 + dd;
        float v = wacc[b * D + d] + bv[d] + x[(size_t)b * S * D + d];
        vs[b][dd] = (v - sMu[b]) * sInv[b] * g1[d] + b1[d];
    }
    __syncthreads();
    float acc[8] = {0.f, 0.f, 0.f, 0.f, 0.f, 0.f, 0.f, 0.f};
#pragma unroll 4
    for (int dd = 0; dd < 32; ++dd) {
        float wv = Wd[(size_t)(d0 + dd) * D + dp];
#pragma unroll
        for (int b = 0; b < 8; ++b) acc[b] += vs[b][dd] * wv;
    }
#pragma unroll
    for (int b = 0; b < 8; ++b) atomicAdd(&hacc[b * D + dp], acc[b]);
}

// ---------------- K6: recompute ln1 row + ReLU + LN2 + classifier -> out -----
// grid 8, block 256.
__global__ void __launch_bounds__(256) k6_final(const float* __restrict__ wacc,
                                                const float* __restrict__ bv,
                                                const float* __restrict__ x,
                                                const float* __restrict__ g1,
                                                const float* __restrict__ b1,
                                                const float* __restrict__ hacc,
                                                const float* __restrict__ bd,
                                                const float* __restrict__ g2,
                                                const float* __restrict__ b2,
                                                const float* __restrict__ Wc,
                                                const float* __restrict__ bc,
                                                float* __restrict__ out) {
    const int b = blockIdx.x;
    const int tid = threadIdx.x;
    float r[4];
    float s = 0.f, ss = 0.f;
#pragma unroll
    for (int i = 0; i < 4; ++i) {
        int e = tid * 4 + i;
        float v = wacc[b * D + e] + bv[e] + x[(size_t)b * S * D + e];
        r[i] = v;
        s += v;
        ss += v * v;
    }
    s = blockReduceSum(s);
    ss = blockReduceSum(ss);
    float mu1 = s * (1.0f / D);
    float inv1 = rsqrtf(ss * (1.0f / D) - mu1 * mu1 + 1e-5f);
    float t[4];
    float s2 = 0.f, ss2 = 0.f;
#pragma unroll
    for (int i = 0; i < 4; ++i) {
        int e = tid * 4 + i;
        float ln1v = (r[i] - mu1) * inv1 * g1[e] + b1[e];
        float h = fmaxf(hacc[b * D + e] + bd[e], 0.f) + ln1v;
        t[i] = h;
        s2 += h;
        ss2 += h * h;
    }
    s2 = blockReduceSum(s2);
    ss2 = blockReduceSum(ss2);
    float mu2 = s2 * (1.0f / D);
    float inv2 = rsqrtf(ss2 * (1.0f / D) - mu2 * mu2 + 1e-5f);
    float p0 = 0.f, p1 = 0.f;
#pragma unroll
    for (int i = 0; i < 4; ++i) {
        int e = tid * 4 + i;
        float l2 = (t[i] - mu2) * inv2 * g2[e] + b2[e];
        p0 += l2 * Wc[e * 2 + 0];
        p1 += l2 * Wc[e * 2 + 1];
    }
    p0 = blockReduceSum(p0);
    p1 = blockReduceSum(p1);
    if (tid == 0) {
        out[b * 2 + 0] = p0 + bc[0];
        out[b * 2 + 1] = p1 + bc[1];
    }
}

extern "C" void kernel_launch(void* const* d_in, const int* in_sizes, int n_in,
                              void* d_out, int out_size, void* d_ws, size_t ws_size,
                              hipStream_t stream) {
    const float* x  = (const float*)d_in[0];
    const float* Wq = (const float*)d_in[1];
    const float* bq = (const float*)d_in[2];
    const float* Wk = (const float*)d_in[3];
    // bk (d_in[4]): constant over t -> cancels in softmax
    const float* Wv = (const float*)d_in[5];
    const float* bv = (const float*)d_in[6];
    const float* Wd = (const float*)d_in[7];
    const float* bd = (const float*)d_in[8];
    const float* g1 = (const float*)d_in[9];
    const float* b1 = (const float*)d_in[10];
    const float* g2 = (const float*)d_in[11];
    const float* b2 = (const float*)d_in[12];
    const float* Wc = (const float*)d_in[13];
    const float* bc = (const float*)d_in[14];
    float* out = (float*)d_out;

    float* ws   = (float*)d_ws;
    // zero region (24584 floats, zeroed by k1): wnum, wacc, hacc, wden
    float* wnum = ws;            // [8,1024] atomic acc
    float* wacc = ws + 8192;     // [8,1024] atomic acc
    float* hacc = ws + 16384;    // [8,1024] atomic acc
    float* wden = ws + 24576;    // [8] atomic acc
    float* q0   = ws + 24584;    // [8,1024]
    float* u    = ws + 32776;    // [8,1024]

    // K1: q0 = x0 @ Wq + bq ; zeroes wnum/wacc/hacc/wden
    k1_q0<<<64, 256, 0, stream>>>(x, Wq, bq, q0, ws);
    // K2: u = Wk @ q0
    k2_u<<<256, 256, 0, stream>>>(Wk, q0, u);
    // K3: attention, raw-exp weighted sums (single x pass)
    k3_attn<<<dim3(128, 8), 256, 0, stream>>>(x, u, wnum, wden);
    // K4: w = wnum/wden ; wacc = w @ Wv
    k4_wv<<<128, 256, 0, stream>>>(wnum, wden, Wv, wacc);
    // K5: LN1 (redundant stats) + @Wd -> hacc
    k5_ln1_wd<<<128, 256, 0, stream>>>(wacc, bv, x, g1, b1, Wd, hacc);
    // K6: ln1 recompute + ReLU + LN2 + classifier
    k6_final<<<8, 256, 0, stream>>>(wacc, bv, x, g1, b1, hacc, bd, g2, b2, Wc, bc, out);
}

// Round 10
// 169.917 us; speedup vs baseline: 1.3993x; 1.0811x over previous
//
#include <hip/hip_runtime.h>
#include <math.h>

#define B 8
#define S 2048
#define D 1024

// ---------------- reduction helpers (256-thread blocks) ----------------
__device__ __forceinline__ float waveReduceSum(float v) {
#pragma unroll
    for (int k = 32; k >= 1; k >>= 1) v += __shfl_xor(v, k, 64);
    return v;
}
__device__ __forceinline__ float waveReduceMax(float v) {
#pragma unroll
    for (int k = 32; k >= 1; k >>= 1) v = fmaxf(v, __shfl_xor(v, k, 64));
    return v;
}
__device__ float blockReduceSum(float v) {
    __shared__ float sm[4];
    int lane = threadIdx.x & 63, wid = threadIdx.x >> 6;
    v = waveReduceSum(v);
    __syncthreads();
    if (lane == 0) sm[wid] = v;
    __syncthreads();
    return sm[0] + sm[1] + sm[2] + sm[3];
}

// ---------------- K1: q0 = x0 @ Wq + bq (non-atomic, full-K per block) -------
// grid 64, block 256. Block owns a 16-wide dp chunk; 16 K-groups of 64.
// Also zeroes the wacc+hacc accumulator region (16384 floats, 256/block).
__global__ void __launch_bounds__(256) k1_q0(const float* __restrict__ x,
                                             const float* __restrict__ Wq,
                                             const float* __restrict__ bq,
                                             float* __restrict__ q0,
                                             float* __restrict__ zero_region) {
    const int tid = threadIdx.x;
    zero_region[blockIdx.x * 256 + tid] = 0.f;  // 64*256 == 16384 exactly

    const int dp0 = blockIdx.x * 16;
    const int dpl = tid & 15, kg = tid >> 4;
    __shared__ float xs[8][1024];
    for (int j = tid; j < 2048; j += 256) {  // 2048 float4 = 8 rows x 256
        int b = j >> 8, off = j & 255;
        ((float4*)xs[b])[off] = ((const float4*)(x + (size_t)b * S * D))[off];
    }
    __syncthreads();
    float acc[8] = {0.f, 0.f, 0.f, 0.f, 0.f, 0.f, 0.f, 0.f};
    const int k0 = kg * 64;
    for (int i = 0; i < 64; ++i) {
        int k = k0 + i;
        float wv = Wq[(size_t)k * D + dp0 + dpl];
#pragma unroll
        for (int b = 0; b < 8; ++b) acc[b] += xs[b][k] * wv;
    }
    __shared__ float red[16 * 16 * 9];  // (kg*16+dpl)*9 + b, pad stride 9
#pragma unroll
    for (int b = 0; b < 8; ++b) red[(kg * 16 + dpl) * 9 + b] = acc[b];
    __syncthreads();
    if (tid < 128) {
        int dpl2 = tid >> 3, b = tid & 7;
        float s = 0.f;
#pragma unroll
        for (int g = 0; g < 16; ++g) s += red[(g * 16 + dpl2) * 9 + b];
        q0[b * D + dp0 + dpl2] = s + bq[dp0 + dpl2];
    }
}

// ---------------- K2: u[b,row] = Wk[row,:] . q0[b,:] (one wave per row) ------
__global__ void __launch_bounds__(256) k2_u(const float* __restrict__ Wk,
                                            const float* __restrict__ q0,
                                            float* __restrict__ u) {
    int wid = (blockIdx.x * 256 + threadIdx.x) >> 6;  // row 0..1023
    int lane = threadIdx.x & 63;
    const float4* Wk4 = (const float4*)(Wk + (size_t)wid * D);
    const float4* q04 = (const float4*)q0;
    float acc[8] = {0.f, 0.f, 0.f, 0.f, 0.f, 0.f, 0.f, 0.f};
#pragma unroll
    for (int i = 0; i < 4; ++i) {
        float4 wv = Wk4[lane + 64 * i];
#pragma unroll
        for (int b = 0; b < 8; ++b) {
            float4 qv = q04[b * 256 + lane + 64 * i];
            acc[b] += wv.x * qv.x + wv.y * qv.y + wv.z * qv.z + wv.w * qv.w;
        }
    }
#pragma unroll
    for (int b = 0; b < 8; ++b) {
        float v = waveReduceSum(acc[b]);
        if (lane == 0) u[b * D + wid] = v;
    }
}

// ---------------- K3: fused scores + online-softmax partials (x once, in regs)
// grid (128, 8), block 256. Block: 16 t's of batch b.
__global__ void __launch_bounds__(256) k3_attn(const float* __restrict__ x,
                                               const float* __restrict__ u,
                                               float* __restrict__ pml,
                                               float* __restrict__ pw) {
    const int b = blockIdx.y;
    const int t0 = blockIdx.x * 16;
    const int tid = threadIdx.x;
    const int wave = tid >> 6, lane = tid & 63;
    const float4* xb4 = (const float4*)(x + (size_t)b * S * D);
    float4 xr[16];
#pragma unroll
    for (int t = 0; t < 16; ++t) xr[t] = xb4[(size_t)(t0 + t) * 256 + tid];
    float4 uv = ((const float4*)(u + b * D))[tid];
    __shared__ float part[16][256];
#pragma unroll
    for (int t = 0; t < 16; ++t)
        part[t][tid] = xr[t].x * uv.x + xr[t].y * uv.y + xr[t].z * uv.z + xr[t].w * uv.w;
    __syncthreads();
    __shared__ float s_sc[16];
#pragma unroll
    for (int r = 0; r < 4; ++r) {
        int t = wave * 4 + r;
        float v = part[t][lane] + part[t][lane + 64] + part[t][lane + 128] + part[t][lane + 192];
        v = waveReduceSum(v);
        if (lane == 0) s_sc[t] = v * 0.03125f;  // 1/sqrt(1024)
    }
    __syncthreads();
    float m = -INFINITY;
#pragma unroll
    for (int t = 0; t < 16; ++t) m = fmaxf(m, s_sc[t]);
    float p[16], l = 0.f;
#pragma unroll
    for (int t = 0; t < 16; ++t) {
        p[t] = __expf(s_sc[t] - m);
        l += p[t];
    }
    float4 wl = {0.f, 0.f, 0.f, 0.f};
#pragma unroll
    for (int t = 0; t < 16; ++t) {
        wl.x += p[t] * xr[t].x;
        wl.y += p[t] * xr[t].y;
        wl.z += p[t] * xr[t].z;
        wl.w += p[t] * xr[t].w;
    }
    const int pidx = b * 128 + blockIdx.x;
    ((float4*)(pw + (size_t)pidx * 1024))[tid] = wl;
    if (tid == 0) {
        pml[pidx * 2 + 0] = m;
        pml[pidx * 2 + 1] = l;
    }
}

// ---------------- K4: combine partials (local slice) + vecmat Wv -> wacc -----
// grid 128, block 256. K-chunk d0=(bid>>2)*32, dp-chunk (bid&3)*256.
__global__ void __launch_bounds__(256) k4_comb_wv(const float* __restrict__ pml,
                                                  const float* __restrict__ pw,
                                                  const float* __restrict__ Wv,
                                                  float* __restrict__ wacc) {
    const int tid = threadIdx.x;
    const int bid = blockIdx.x;
    const int d0 = (bid >> 2) * 32;
    const int dp = (bid & 3) * 256 + tid;
    const int wave = tid >> 6, lane = tid & 63;
    __shared__ float pm[8][128], pl[8][128], sc[8][128];
    __shared__ float sM[8], sL[8];
    __shared__ float vs[8][32];
    for (int j = tid; j < 1024; j += 256) {
        int b = j >> 7, blk = j & 127;
        pm[b][blk] = pml[(b * 128 + blk) * 2 + 0];
        pl[b][blk] = pml[(b * 128 + blk) * 2 + 1];
    }
    __syncthreads();
    // per-batch M and L: wave w handles batches w and w+4
#pragma unroll
    for (int h = 0; h < 2; ++h) {
        int b = wave + h * 4;
        float mv = fmaxf(pm[b][lane], pm[b][lane + 64]);
        float M = waveReduceMax(mv);
        float lp = __expf(pm[b][lane] - M) * pl[b][lane] +
                   __expf(pm[b][lane + 64] - M) * pl[b][lane + 64];
        float L = waveReduceSum(lp);
        if (lane == 0) {
            sM[b] = M;
            sL[b] = L;
        }
    }
    __syncthreads();
    for (int j = tid; j < 1024; j += 256) {
        int b = j >> 7, blk = j & 127;
        sc[b][blk] = __expf(pm[b][blk] - sM[b]);
    }
    __syncthreads();
    // combine: thread -> (b = tid>>5, dd = tid&31)
    {
        int b = tid >> 5, dd = tid & 31, d = d0 + dd;
        float acc = 0.f;
#pragma unroll 4
        for (int blk = 0; blk < 128; ++blk)
            acc += sc[b][blk] * pw[(size_t)(b * 128 + blk) * 1024 + d];
        vs[b][dd] = acc / sL[b];
    }
    __syncthreads();
    float acc[8] = {0.f, 0.f, 0.f, 0.f, 0.f, 0.f, 0.f, 0.f};
#pragma unroll 4
    for (int dd = 0; dd < 32; ++dd) {
        float wv = Wv[(size_t)(d0 + dd) * D + dp];
#pragma unroll
        for (int b = 0; b < 8; ++b) acc[b] += vs[b][dd] * wv;
    }
#pragma unroll
    for (int b = 0; b < 8; ++b) atomicAdd(&wacc[b * D + dp], acc[b]);
}

// ---------------- K5: LN1 (wave-parallel stats) + vecmat Wd -> hacc ----------
// grid 128, block 256. Stats code validated in R8's kC phase 2 (absmax 0.0).
__global__ void __launch_bounds__(256) k5_ln1_wd(const float* __restrict__ wacc,
                                                 const float* __restrict__ bv,
                                                 const float* __restrict__ x,
                                                 const float* __restrict__ g1,
                                                 const float* __restrict__ b1,
                                                 const float* __restrict__ Wd,
                                                 float* __restrict__ hacc) {
    const int tid = threadIdx.x;
    const int bid = blockIdx.x;
    const int d0 = (bid >> 2) * 32;
    const int dp = (bid & 3) * 256 + tid;
    const int wave = tid >> 6, lane = tid & 63;
    __shared__ float sMu[8], sInv[8], vs[8][32];
    {
        const float4* wacc4 = (const float4*)wacc;
        const float4* bv4 = (const float4*)bv;
#pragma unroll
        for (int h = 0; h < 2; ++h) {
            int b = wave + h * 4;
            const float4* xb4r = (const float4*)(x + (size_t)b * S * D);
            float s = 0.f, ss = 0.f;
#pragma unroll
            for (int i = 0; i < 4; ++i) {
                int idx = lane + 64 * i;
                float4 wv = wacc4[b * 256 + idx];
                float4 bb = bv4[idx];
                float4 xv = xb4r[idx];
                float v0 = wv.x + bb.x + xv.x;
                float v1 = wv.y + bb.y + xv.y;
                float v2 = wv.z + bb.z + xv.z;
                float v3 = wv.w + bb.w + xv.w;
                s += v0 + v1 + v2 + v3;
                ss += v0 * v0 + v1 * v1 + v2 * v2 + v3 * v3;
            }
            s = waveReduceSum(s);
            ss = waveReduceSum(ss);
            if (lane == 0) {
                float mu = s * (1.0f / D);
                sMu[b] = mu;
                sInv[b] = rsqrtf(ss * (1.0f / D) - mu * mu + 1e-5f);
            }
        }
    }
    __syncthreads();
    {
        int b = tid >> 5, dd = tid & 31, d = d0 + dd;
        float v = wacc[b * D + d] + bv[d] + x[(size_t)b * S * D + d];
        vs[b][dd] = (v - sMu[b]) * sInv[b] * g1[d] + b1[d];
    }
    __syncthreads();
    float acc[8] = {0.f, 0.f, 0.f, 0.f, 0.f, 0.f, 0.f, 0.f};
#pragma unroll 4
    for (int dd = 0; dd < 32; ++dd) {
        float wv = Wd[(size_t)(d0 + dd) * D + dp];
#pragma unroll
        for (int b = 0; b < 8; ++b) acc[b] += vs[b][dd] * wv;
    }
#pragma unroll
    for (int b = 0; b < 8; ++b) atomicAdd(&hacc[b * D + dp], acc[b]);
}

// ---------------- K6: recompute ln1 row + ReLU + LN2 + classifier -> out -----
// grid 8, block 256.
__global__ void __launch_bounds__(256) k6_final(const float* __restrict__ wacc,
                                                const float* __restrict__ bv,
                                                const float* __restrict__ x,
                                                const float* __restrict__ g1,
                                                const float* __restrict__ b1,
                                                const float* __restrict__ hacc,
                                                const float* __restrict__ bd,
                                                const float* __restrict__ g2,
                                                const float* __restrict__ b2,
                                                const float* __restrict__ Wc,
                                                const float* __restrict__ bc,
                                                float* __restrict__ out) {
    const int b = blockIdx.x;
    const int tid = threadIdx.x;
    float r[4];
    float s = 0.f, ss = 0.f;
#pragma unroll
    for (int i = 0; i < 4; ++i) {
        int e = tid * 4 + i;
        float v = wacc[b * D + e] + bv[e] + x[(size_t)b * S * D + e];
        r[i] = v;
        s += v;
        ss += v * v;
    }
    s = blockReduceSum(s);
    ss = blockReduceSum(ss);
    float mu1 = s * (1.0f / D);
    float inv1 = rsqrtf(ss * (1.0f / D) - mu1 * mu1 + 1e-5f);
    float t[4];
    float s2 = 0.f, ss2 = 0.f;
#pragma unroll
    for (int i = 0; i < 4; ++i) {
        int e = tid * 4 + i;
        float ln1v = (r[i] - mu1) * inv1 * g1[e] + b1[e];
        float h = fmaxf(hacc[b * D + e] + bd[e], 0.f) + ln1v;
        t[i] = h;
        s2 += h;
        ss2 += h * h;
    }
    s2 = blockReduceSum(s2);
    ss2 = blockReduceSum(ss2);
    float mu2 = s2 * (1.0f / D);
    float inv2 = rsqrtf(ss2 * (1.0f / D) - mu2 * mu2 + 1e-5f);
    float p0 = 0.f, p1 = 0.f;
#pragma unroll
    for (int i = 0; i < 4; ++i) {
        int e = tid * 4 + i;
        float l2 = (t[i] - mu2) * inv2 * g2[e] + b2[e];
        p0 += l2 * Wc[e * 2 + 0];
        p1 += l2 * Wc[e * 2 + 1];
    }
    p0 = blockReduceSum(p0);
    p1 = blockReduceSum(p1);
    if (tid == 0) {
        out[b * 2 + 0] = p0 + bc[0];
        out[b * 2 + 1] = p1 + bc[1];
    }
}

extern "C" void kernel_launch(void* const* d_in, const int* in_sizes, int n_in,
                              void* d_out, int out_size, void* d_ws, size_t ws_size,
                              hipStream_t stream) {
    const float* x  = (const float*)d_in[0];
    const float* Wq = (const float*)d_in[1];
    const float* bq = (const float*)d_in[2];
    const float* Wk = (const float*)d_in[3];
    // bk (d_in[4]): constant over t -> cancels in softmax
    const float* Wv = (const float*)d_in[5];
    const float* bv = (const float*)d_in[6];
    const float* Wd = (const float*)d_in[7];
    const float* bd = (const float*)d_in[8];
    const float* g1 = (const float*)d_in[9];
    const float* b1 = (const float*)d_in[10];
    const float* g2 = (const float*)d_in[11];
    const float* b2 = (const float*)d_in[12];
    const float* Wc = (const float*)d_in[13];
    const float* bc = (const float*)d_in[14];
    float* out = (float*)d_out;

    float* ws   = (float*)d_ws;
    float* q0   = ws;           // [8,1024] written whole by K1
    float* u    = ws + 8192;    // [8,1024]
    float* wacc = ws + 16384;   // [8,1024] zeroed by K1, atomics in K4
    float* hacc = ws + 24576;   // [8,1024] zeroed by K1, atomics in K5
    float* pml  = ws + 32768;   // [8,128,2]
    float* pw   = ws + 34816;   // [8,128,1024] (byte off 139264, 16B-aligned)

    // K1: q0 = x0 @ Wq + bq ; also zeroes wacc+hacc (contiguous 16384 floats)
    k1_q0<<<64, 256, 0, stream>>>(x, Wq, bq, q0, wacc);
    // K2: u = Wk @ q0
    k2_u<<<256, 256, 0, stream>>>(Wk, q0, u);
    // K3: attention partials (single x pass)
    k3_attn<<<dim3(128, 8), 256, 0, stream>>>(x, u, pml, pw);
    // K4: combine + @Wv -> wacc
    k4_comb_wv<<<128, 256, 0, stream>>>(pml, pw, Wv, wacc);
    // K5: LN1 (wave-parallel stats) + @Wd -> hacc
    k5_ln1_wd<<<128, 256, 0, stream>>>(wacc, bv, x, g1, b1, Wd, hacc);
    // K6: ln1 recompute + ReLU + LN2 + classifier
    k6_final<<<8, 256, 0, stream>>>(wacc, bv, x, g1, b1, hacc, bd, g2, b2, Wc, bc, out);
}